// Round 1
// baseline (197.685 us; speedup 1.0000x reference)
//
#include <hip/hip_runtime.h>

// Problem constants
#define HH 256
#define WW 256
#define BB 4
#define CC 3
#define HW 65536          // H*W
#define NM 24             // 2*B*C masks (0..11 lab, 12..23 pred)
#define NBLK 1024         // fused grid: 4 blocks/CU x 256 CUs, all co-resident
#define BIGF 1e9f
#define LIMITF 331776.0f  // 576*576
#define EPSF 1e-5f

// Barrier flag magics. Deliberately NOT byte-repeating: the harness poison
// fill writes a repeated byte pattern, which can never collide with these.
#define MAGIC1 0x1B7E55ED
#define MAGIC2 0x2C8F66EE
#define MAGIC3 0x3D9A77EF

// R6: cooperative grid.sync ~90us/sync at 1024 blocks -> never use it.
// R10: fuse all 4 kernels into ONE dispatch with manual co-resident grid
// barriers (split-K pattern: release fence -> arrive flag; block0 polls ->
// go flag; acquire fence after spin). Residency guaranteed by capacity math:
// 1024 blocks of 256 thr = 4/CU exactly; __launch_bounds__(256,4) caps
// VGPR<=128 (4 waves/SIMD); static LDS 11.9KB -> 47.6KB/CU < 160KB.
// Flags are self-cleaning (block0 zeroes them at the end) so correctness
// does not depend on whether the harness re-poisons ws between iterations.

struct GFlags {
    int arr1[NBLK];
    int arr2[NBLK];
    int arr3[NBLK];
    int go1;
    int go2;
};

__device__ __forceinline__ int ldf(const int* p) {
    return __hip_atomic_load(p, __ATOMIC_RELAXED, __HIP_MEMORY_SCOPE_AGENT);
}
__device__ __forceinline__ void stf(int* p, int v) {
    __hip_atomic_store(p, v, __ATOMIC_RELAXED, __HIP_MEMORY_SCOPE_AGENT);
}

// Manual grid barrier across all NBLK co-resident blocks.
// Release side: each wave's stores are in L2 at the __syncthreads (compiler
// emits s_waitcnt vmcnt(0) before s_barrier); tid0's __threadfence() (agent
// acq_rel) emits buffer_wbl2 sc1 pushing the XCD L2 to L3/HBM before the
// arrive-flag store. Acquire side: tid0's __threadfence() after the spin
// emits buffer_inv (drops stale vL1 of this CU + XCD L2) before any thread
// of the block issues post-barrier reads (__syncthreads orders them).
__device__ __forceinline__ void gbar(int bid, int* arr, int* go, int magic) {
    __syncthreads();
    if (threadIdx.x == 0) { __threadfence(); stf(&arr[bid], magic); }
    if (bid == 0) {
        int i0 = threadIdx.x << 2;          // 256 threads x 4 flags each
        #pragma unroll
        for (int k = 0; k < 4; ++k)
            while (ldf(&arr[i0 + k]) != magic) __builtin_amdgcn_s_sleep(2);
        __syncthreads();
        if (threadIdx.x == 0) stf(go, magic);
    }
    if (threadIdx.x == 0) {
        while (ldf(go) != magic) __builtin_amdgcn_s_sleep(2);
        __threadfence();
    }
    __syncthreads();
}

__global__ __launch_bounds__(256, 4) void fused(
        const float* __restrict__ pred, const int* __restrict__ lab,
        float* __restrict__ dbuf, float* __restrict__ blkmax,
        float* __restrict__ psum, int* __restrict__ pfg,
        unsigned char* __restrict__ codes, GFlags* __restrict__ fl,
        float* __restrict__ out) {
    // Static LDS union of all phases: 11520 + 192 + ~180 B = 11.9 KB.
    __shared__ unsigned long long zm[6][4];
    __shared__ float tile[320 * 9];   // rows 0..319 = k -32..287, stride 9
    __shared__ float wmax[4];
    __shared__ float inv[NM];
    __shared__ float wsum[4];
    __shared__ int   wfg[4];
    __shared__ float bsum[4];
    __shared__ int   bfg[4];

    const int bid = blockIdx.x;

    // ------------------------------------------------------------------
    // Phase 1: row-wise squared distance to nearest zero (all 6 masks of
    // one (batch,row)) + per-pixel code byte. Identical math to k_rowpass.
    // ------------------------------------------------------------------
    {
        int b = bid >> 8;
        int i = bid & 255;
        int j = threadIdx.x;

        int lv = lab[(b << 16) + (i << 8) + j];
        const float* pb = pred + (((size_t)(b * 3)) << 16) + (i << 8) + j;
        float p0 = pb[0];
        float p1 = pb[(size_t)1 << 16];
        float p2 = pb[(size_t)2 << 16];
        int am = 0; float v = p0;
        if (p1 > v) { am = 1; v = p1; }
        if (p2 > v) { am = 2; }

        codes[(b << 16) + (i << 8) + j] = (unsigned char)(lv | (am << 2));

        int w = threadIdx.x >> 6;
        #pragma unroll
        for (int c = 0; c < 3; ++c) {
            unsigned long long zl = __ballot(lv != c);
            unsigned long long zp = __ballot(am != c);
            if ((threadIdx.x & 63) == 0) { zm[c][w] = zl; zm[3 + c][w] = zp; }
        }
        __syncthreads();

        #pragma unroll
        for (int t = 0; t < 6; ++t) {
            int bestd = 512;  // sentinel > any possible distance (<=255)
            #pragma unroll
            for (int w2 = 0; w2 < 4; ++w2) {
                unsigned long long z = zm[t][w2];
                int basew = w2 << 6;
                int rel = j - basew;
                unsigned long long mle;   // bits at positions <= rel
                if (rel >= 63)      mle = ~0ULL;
                else if (rel < 0)   mle = 0ULL;
                else                mle = (2ULL << rel) - 1ULL;
                unsigned long long zlo = z & mle;
                if (zlo) {
                    int p = basew + 63 - __clzll(zlo);
                    int d = j - p;
                    if (d < bestd) bestd = d;
                }
                unsigned long long zr = z & ~mle;
                if (zr) {
                    int p = basew + __ffsll(zr) - 1;
                    int d = p - j;
                    if (d < bestd) bestd = d;
                }
            }
            float d1 = (bestd >= 512) ? BIGF : (float)(bestd * bestd);
            int c = (t < 3) ? t : (t - 3);
            int m = ((t < 3) ? 0 : 12) + b * 3 + c;
            dbuf[(((size_t)m) << 16) + (i << 8) + j] = d1;
        }
    }

    gbar(bid, fl->arr1, &fl->go1, MAGIC1);

    // ------------------------------------------------------------------
    // Phase 2: column min-plus with wave-uniform exact window. Identical
    // math to k_colpass. Blocks >= 768 idle through to the barrier.
    // ------------------------------------------------------------------
    if (bid < NM * 32) {
        int m = bid >> 5;
        int j0 = (bid & 31) << 3;
        float* base = dbuf + (((size_t)m) << 16);

        {   // guard rows (k=-32..-1, 256..287) = BIG
            int t = threadIdx.x;
            int gr = t >> 3, gc = t & 7;
            tile[gr * 9 + gc] = BIGF;
            tile[(288 + gr) * 9 + gc] = BIGF;
        }
        #pragma unroll
        for (int it = 0; it < 2; ++it) {
            int f = (it << 8) + threadIdx.x;   // float4 index 0..511
            int row = f >> 1, half = f & 1;
            float4 v4 = *(const float4*)(base + (row << 8) + j0 + (half << 2));
            int lb = (row + 32) * 9 + (half << 2);
            tile[lb + 0] = v4.x; tile[lb + 1] = v4.y;
            tile[lb + 2] = v4.z; tile[lb + 3] = v4.w;
        }
        __syncthreads();

        int jj = threadIdx.x & 7;
        int ib = threadIdx.x >> 3;   // 0..31

        float acc[8];
        float dmax = 0.0f;
        #pragma unroll
        for (int r = 0; r < 8; ++r) {
            acc[r] = tile[(ib + (r << 5) + 32) * 9 + jj];   // k=i candidate
            dmax = fmaxf(dmax, acc[r]);
        }
        #pragma unroll
        for (int off = 32; off; off >>= 1)
            dmax = fmaxf(dmax, __shfl_xor(dmax, off, 64));
        int Rmax = (int)sqrtf(dmax) + 1;
        if (Rmax > 255) Rmax = 255;

        if (Rmax <= 32) {
            // Fast path: guards cover k=i+o fully; dk^2 = o^2 wave-scalar.
            for (int o = -Rmax; o <= Rmax; ++o) {
                float o2 = (float)(o * o);
                #pragma unroll
                for (int r = 0; r < 8; ++r)
                    acc[r] = fminf(acc[r], o2 + tile[(ib + (r << 5) + 32 + o) * 9 + jj]);
            }
        } else {
            // Slow path (BIG rows in wave): clamped candidates, exact.
            for (int o = -Rmax; o <= Rmax; ++o) {
                #pragma unroll
                for (int r = 0; r < 8; ++r) {
                    int i = ib + (r << 5);
                    int k = i + o;
                    k = (k < 0) ? 0 : ((k > 255) ? 255 : k);
                    float dk = (float)(k - i);
                    acc[r] = fminf(acc[r], fmaf(dk, dk, tile[(k + 32) * 9 + jj]));
                }
            }
        }

        float lmax = 0.0f;
        #pragma unroll
        for (int r = 0; r < 8; ++r) {
            int i = ib + (r << 5);
            base[(i << 8) + j0 + jj] = acc[r];
            lmax = fmaxf(lmax, acc[r]);
        }
        #pragma unroll
        for (int off = 32; off; off >>= 1)
            lmax = fmaxf(lmax, __shfl_down(lmax, off, 64));
        if ((threadIdx.x & 63) == 0) wmax[threadIdx.x >> 6] = lmax;
        __syncthreads();
        if (threadIdx.x == 0)
            blkmax[bid] = fmaxf(fmaxf(wmax[0], wmax[1]), fmaxf(wmax[2], wmax[3]));
    }

    gbar(bid, fl->arr2, &fl->go2, MAGIC2);

    // ------------------------------------------------------------------
    // Phase 3: per-pixel cosine sim -> per-block partials. Identical math
    // to k_final. Then signal arr3 (no full barrier: only block 0 consumes).
    // ------------------------------------------------------------------
    {
        if (threadIdx.x < NM) {
            const float* bm = blkmax + (threadIdx.x << 5);
            float v = 0.0f;
            #pragma unroll
            for (int s = 0; s < 32; ++s) v = fmaxf(v, bm[s]);
            inv[threadIdx.x] = 1.0f / (fminf(sqrtf(v), LIMITF) + EPSF);
        }
        __syncthreads();

        int b = bid >> 8;
        int pix = ((bid & 255) << 8) + threadIdx.x;

        int code = codes[(b << 16) + pix];
        int lv = code & 3;
        int am = code >> 2;

        float slab = 0.0f, spred = 0.0f;
        #pragma unroll
        for (int c = 0; c < 3; ++c) {
            int ml = b * 3 + c;
            float dl = dbuf[(((size_t)ml) << 16) + pix];
            slab += sqrtf(dl) * inv[ml];
            float dp = dbuf[(((size_t)(ml + 12)) << 16) + pix];
            spred += sqrtf(dp) * inv[ml + 12];
        }

        float dot = spred * slab + ((am == lv) ? 1.0f : 0.0f);
        float na = sqrtf(spred * spred + 1.0f);
        float nb = sqrtf(slab * slab + 1.0f);
        float sim = dot / (fmaxf(na, 1e-8f) * fmaxf(nb, 1e-8f));

        unsigned long long fg = __ballot(lv > 0);

        #pragma unroll
        for (int off = 32; off; off >>= 1)
            sim += __shfl_down(sim, off, 64);
        if ((threadIdx.x & 63) == 0) {
            wsum[threadIdx.x >> 6] = sim;
            wfg[threadIdx.x >> 6] = (fg != 0ULL) ? 1 : 0;
        }
        __syncthreads();
        if (threadIdx.x == 0) {
            psum[bid] = wsum[0] + wsum[1] + wsum[2] + wsum[3];
            pfg[bid] = wfg[0] | wfg[1] | wfg[2] | wfg[3];
            __threadfence();               // release psum/pfg before signal
            stf(&fl->arr3[bid], MAGIC3);
        }
    }

    if (bid != 0) return;

    // ------------------------------------------------------------------
    // Phase 4 (block 0 only): wait for all partials, reduce deterministically
    // (identical order to k_finalize -> bit-exact), write loss, clean flags.
    // ------------------------------------------------------------------
    {
        int i0 = threadIdx.x << 2;
        #pragma unroll
        for (int k = 0; k < 4; ++k)
            while (ldf(&fl->arr3[i0 + k]) != MAGIC3) __builtin_amdgcn_s_sleep(2);
        __syncthreads();
        if (threadIdx.x == 0) __threadfence();   // acquire: inv before reads
        __syncthreads();

        int t = threadIdx.x;
        int b = t >> 6, l = t & 63;
        int base = (b << 8) + l;
        float s = psum[base] + psum[base + 64] + psum[base + 128] + psum[base + 192];
        int f = pfg[base] | pfg[base + 64] | pfg[base + 128] | pfg[base + 192];
        #pragma unroll
        for (int off = 32; off; off >>= 1) {
            s += __shfl_down(s, off, 64);
            f |= __shfl_down(f, off, 64);
        }
        if (l == 0) { bsum[b] = s; bfg[b] = f; }
        __syncthreads();
        if (t == 0) {
            float loss = 0.0f;
            for (int bb = 0; bb < BB; ++bb) {
                float lb = 1.0f - bsum[bb] * (1.0f / (float)HW);
                if (bfg[bb]) loss += lb;
            }
            loss *= (1.0f / (float)BB);
            if (isnan(loss)) loss = 0.0f;
            else if (isinf(loss)) loss = (loss > 0.0f) ? 1.0f : 0.0f;
            out[0] = loss;
        }

        // Self-clean barrier state for the next timed iteration (works
        // whether or not the harness re-poisons ws between iterations).
        __syncthreads();
        #pragma unroll
        for (int k = 0; k < 4; ++k) {
            fl->arr1[i0 + k] = 0;
            fl->arr2[i0 + k] = 0;
            fl->arr3[i0 + k] = 0;
        }
        if (t == 0) { fl->go1 = 0; fl->go2 = 0; }
    }
}

extern "C" void kernel_launch(void* const* d_in, const int* in_sizes, int n_in,
                              void* d_out, int out_size, void* d_ws, size_t ws_size,
                              hipStream_t stream) {
    (void)in_sizes; (void)n_in; (void)out_size; (void)ws_size;
    const float* pred = (const float*)d_in[0];   // [4,3,256,256] f32
    const int*   lab  = (const int*)d_in[1];     // [4,256,256] i32

    char* wsb = (char*)d_ws;
    float* dbuf   = (float*)wsb;                                  // 6 MB
    size_t off    = (size_t)NM * HW * sizeof(float);
    float* blkmax = (float*)(wsb + off);          off += 768 * sizeof(float);
    float* psum   = (float*)(wsb + off);          off += 1024 * sizeof(float);
    int*   pfg    = (int*)  (wsb + off);          off += 1024 * sizeof(int);
    unsigned char* codes = (unsigned char*)(wsb + off);           // 256 KB
    off += (size_t)BB * HW;
    GFlags* fl = (GFlags*)(wsb + off);                            // 12 KB

    // ONE dispatch: 1024 blocks co-resident (4/CU), manual grid barriers.
    fused<<<NBLK, 256, 0, stream>>>(pred, lab, dbuf, blkmax, psum, pfg,
                                    codes, fl, (float*)d_out);
}

// Round 2
// 90.620 us; speedup vs baseline: 2.1815x; 2.1815x over previous
//
#include <hip/hip_runtime.h>

// Problem constants
#define HH 256
#define WW 256
#define BB 4
#define CC 3
#define HW 65536          // H*W
#define NM 24             // 2*B*C masks (0..11 lab, 12..23 pred)
#define NBLK 1024         // fused grid: 4 blocks/CU x 256 CUs, all co-resident
#define BIGF 1e9f
#define LIMITF 331776.0f  // 576*576
#define EPSF 1e-5f

// R6: cooperative grid.sync ~90us. R10: manual barrier with __threadfence
// (buffer_wbl2/buffer_inv per block) ~60-70us/barrier -- the L2
// writeback/invalidate walk is the cost, not the counting.
// R11: NO cache maintenance anywhere. All cross-block data moves through the
// coherent point (memory-side Infinity Cache) via relaxed agent-scope atomic
// loads/stores (the same lowering that makes cross-XCD atomicAdd work,
// learn_hip m20). A store is globally visible once vmcnt retires, and the
// compiler drains vmcnt at every __syncthreads. Barriers are pure counting:
// 64-cell hierarchical arrive -> cell leader polls super -> cell-go word.
// codes[] needs no coherence: phase-3 block bid reads exactly the bytes
// phase-1 block bid wrote (same CU, L1-local).

#define NCELL 64
#define CSTR  32          // ints between cells = 128 B (one cacheline)

struct Flags {
    int cells[3 * NCELL * CSTR];   // [bar][cell][0]=count, [1]=go
    int super1; int p1[31];
    int super2; int p2[31];
    int super3; int p3[31];
};

__device__ __forceinline__ float ldc(const float* p) {   // coherent load (L3)
    return __hip_atomic_load((float*)p, __ATOMIC_RELAXED, __HIP_MEMORY_SCOPE_AGENT);
}
__device__ __forceinline__ void stc(float* p, float v) { // coherent store (L3)
    __hip_atomic_store(p, v, __ATOMIC_RELAXED, __HIP_MEMORY_SCOPE_AGENT);
}
__device__ __forceinline__ int ldi(const int* p) {
    return __hip_atomic_load((int*)p, __ATOMIC_RELAXED, __HIP_MEMORY_SCOPE_AGENT);
}
__device__ __forceinline__ void sti(int* p, int v) {
    __hip_atomic_store(p, v, __ATOMIC_RELAXED, __HIP_MEMORY_SCOPE_AGENT);
}
__device__ __forceinline__ int faddi(int* p) {
    return __hip_atomic_fetch_add(p, 1, __ATOMIC_RELAXED, __HIP_MEMORY_SCOPE_AGENT);
}

// Counting-only grid barrier. Preconditions: all cross-block data written via
// stc/sti (already at coherent point when vmcnt retires); __syncthreads
// drains vmcnt for every wave (compiler-guaranteed, m97 asm evidence).
// 1024 blocks = 64 cells x 16 arrivals. Leader (16th arriver of its cell)
// bumps super, polls super==64, then releases its cell's go word; the other
// 15 poll the cell-local go line. Max 64 pollers on super, <=15 per go line.
__device__ __forceinline__ void gbar(int bid, int* cells, int* sup) {
    __syncthreads();
    if (threadIdx.x == 0) {
        asm volatile("s_waitcnt vmcnt(0)" ::: "memory");
        int* cell = cells + (bid & 63) * CSTR;
        int r = faddi(&cell[0]);
        if (r == 15) {
            faddi(sup);
            while (ldi(sup) != NCELL) __builtin_amdgcn_s_sleep(8);
            sti(&cell[1], 1);
        } else {
            while (ldi(&cell[1]) != 1) __builtin_amdgcn_s_sleep(8);
        }
    }
    __syncthreads();
}

// Tiny pre-kernel: zero barrier state (poison-proof, runs every iteration).
__global__ __launch_bounds__(256) void k_zero(Flags* fl) {
    int t = threadIdx.x;
    for (int i = t; i < 3 * NCELL; i += 256) {
        fl->cells[i * CSTR + 0] = 0;
        fl->cells[i * CSTR + 1] = 0;
    }
    if (t == 0) { fl->super1 = 0; fl->super2 = 0; fl->super3 = 0; }
}

__global__ __launch_bounds__(256, 4) void fused(
        const float* __restrict__ pred, const int* __restrict__ lab,
        float* __restrict__ dbuf, float* __restrict__ blkmax,
        float* __restrict__ psum, int* __restrict__ pfg,
        unsigned char* __restrict__ codes, Flags* __restrict__ fl,
        float* __restrict__ out) {
    __shared__ unsigned long long zm[6][4];
    __shared__ float tile[320 * 9];   // rows 0..319 = k -32..287, stride 9
    __shared__ float wmax[4];
    __shared__ float inv[NM];
    __shared__ float wsum[4];
    __shared__ int   wfg[4];
    __shared__ float bsum[4];
    __shared__ int   bfg[4];
    __shared__ int   iswin;

    const int bid = blockIdx.x;
    int* c1 = fl->cells;
    int* c2 = fl->cells + NCELL * CSTR;
    int* c3 = fl->cells + 2 * NCELL * CSTR;

    // ------------------------------------------------------------------
    // Phase 1: row-wise squared distance to nearest zero (6 masks of one
    // (batch,row)) + code byte. Identical math to k_rowpass.
    // dbuf stores are coherent (read cross-block in phase 2).
    // ------------------------------------------------------------------
    {
        int b = bid >> 8;
        int i = bid & 255;
        int j = threadIdx.x;

        int lv = lab[(b << 16) + (i << 8) + j];
        const float* pb = pred + (((size_t)(b * 3)) << 16) + (i << 8) + j;
        float p0 = pb[0];
        float p1 = pb[(size_t)1 << 16];
        float p2 = pb[(size_t)2 << 16];
        int am = 0; float v = p0;
        if (p1 > v) { am = 1; v = p1; }
        if (p2 > v) { am = 2; }

        codes[(b << 16) + (i << 8) + j] = (unsigned char)(lv | (am << 2));

        int w = threadIdx.x >> 6;
        #pragma unroll
        for (int c = 0; c < 3; ++c) {
            unsigned long long zl = __ballot(lv != c);
            unsigned long long zp = __ballot(am != c);
            if ((threadIdx.x & 63) == 0) { zm[c][w] = zl; zm[3 + c][w] = zp; }
        }
        __syncthreads();

        #pragma unroll
        for (int t = 0; t < 6; ++t) {
            int bestd = 512;  // sentinel > any possible distance (<=255)
            #pragma unroll
            for (int w2 = 0; w2 < 4; ++w2) {
                unsigned long long z = zm[t][w2];
                int basew = w2 << 6;
                int rel = j - basew;
                unsigned long long mle;
                if (rel >= 63)      mle = ~0ULL;
                else if (rel < 0)   mle = 0ULL;
                else                mle = (2ULL << rel) - 1ULL;
                unsigned long long zlo = z & mle;
                if (zlo) {
                    int p = basew + 63 - __clzll(zlo);
                    int d = j - p;
                    if (d < bestd) bestd = d;
                }
                unsigned long long zr = z & ~mle;
                if (zr) {
                    int p = basew + __ffsll(zr) - 1;
                    int d = p - j;
                    if (d < bestd) bestd = d;
                }
            }
            float d1 = (bestd >= 512) ? BIGF : (float)(bestd * bestd);
            int c = (t < 3) ? t : (t - 3);
            int m = ((t < 3) ? 0 : 12) + b * 3 + c;
            stc(&dbuf[(((size_t)m) << 16) + (i << 8) + j], d1);
        }
    }

    gbar(bid, c1, &fl->super1);

    // ------------------------------------------------------------------
    // Phase 2: column min-plus, wave-uniform exact window. Identical math
    // to k_colpass. Staging loads + result stores are coherent.
    // Blocks >= 768 idle through to the barrier.
    // ------------------------------------------------------------------
    if (bid < NM * 32) {
        int m = bid >> 5;
        int j0 = (bid & 31) << 3;
        float* base = dbuf + (((size_t)m) << 16);

        {   // guard rows (k=-32..-1, 256..287) = BIG
            int t = threadIdx.x;
            int gr = t >> 3, gc = t & 7;
            tile[gr * 9 + gc] = BIGF;
            tile[(288 + gr) * 9 + gc] = BIGF;
        }
        // Stage 256x8 slab into rows 32..287 (coherent scalar loads).
        #pragma unroll
        for (int it = 0; it < 2; ++it) {
            int f = (it << 8) + threadIdx.x;   // 8-float group index 0..511
            int row = f >> 1, half = f & 1;
            const float* src = base + (row << 8) + j0 + (half << 2);
            int lb = (row + 32) * 9 + (half << 2);
            tile[lb + 0] = ldc(src + 0);
            tile[lb + 1] = ldc(src + 1);
            tile[lb + 2] = ldc(src + 2);
            tile[lb + 3] = ldc(src + 3);
        }
        __syncthreads();

        int jj = threadIdx.x & 7;
        int ib = threadIdx.x >> 3;   // 0..31

        float acc[8];
        float dmax = 0.0f;
        #pragma unroll
        for (int r = 0; r < 8; ++r) {
            acc[r] = tile[(ib + (r << 5) + 32) * 9 + jj];   // k=i candidate
            dmax = fmaxf(dmax, acc[r]);
        }
        #pragma unroll
        for (int off = 32; off; off >>= 1)
            dmax = fmaxf(dmax, __shfl_xor(dmax, off, 64));
        int Rmax = (int)sqrtf(dmax) + 1;
        if (Rmax > 255) Rmax = 255;

        if (Rmax <= 32) {
            // Fast path: guards cover k=i+o fully; dk^2 = o^2 wave-scalar.
            for (int o = -Rmax; o <= Rmax; ++o) {
                float o2 = (float)(o * o);
                #pragma unroll
                for (int r = 0; r < 8; ++r)
                    acc[r] = fminf(acc[r], o2 + tile[(ib + (r << 5) + 32 + o) * 9 + jj]);
            }
        } else {
            // Slow path (BIG rows in wave): clamped candidates, exact.
            for (int o = -Rmax; o <= Rmax; ++o) {
                #pragma unroll
                for (int r = 0; r < 8; ++r) {
                    int i = ib + (r << 5);
                    int k = i + o;
                    k = (k < 0) ? 0 : ((k > 255) ? 255 : k);
                    float dk = (float)(k - i);
                    acc[r] = fminf(acc[r], fmaf(dk, dk, tile[(k + 32) * 9 + jj]));
                }
            }
        }

        float lmax = 0.0f;
        #pragma unroll
        for (int r = 0; r < 8; ++r) {
            int i = ib + (r << 5);
            stc(&base[(i << 8) + j0 + jj], acc[r]);
            lmax = fmaxf(lmax, acc[r]);
        }
        #pragma unroll
        for (int off = 32; off; off >>= 1)
            lmax = fmaxf(lmax, __shfl_down(lmax, off, 64));
        if ((threadIdx.x & 63) == 0) wmax[threadIdx.x >> 6] = lmax;
        __syncthreads();
        if (threadIdx.x == 0)
            stc(&blkmax[bid], fmaxf(fmaxf(wmax[0], wmax[1]), fmaxf(wmax[2], wmax[3])));
    }

    gbar(bid, c2, &fl->super2);

    // ------------------------------------------------------------------
    // Phase 3: per-pixel cosine sim -> per-block partials. Identical math
    // to k_final. codes is L1-local (written by this very block in ph1).
    // ------------------------------------------------------------------
    {
        if (threadIdx.x < NM) {
            const float* bm = blkmax + (threadIdx.x << 5);
            float v = 0.0f;
            #pragma unroll
            for (int s = 0; s < 32; ++s) v = fmaxf(v, ldc(&bm[s]));
            inv[threadIdx.x] = 1.0f / (fminf(sqrtf(v), LIMITF) + EPSF);
        }
        __syncthreads();

        int b = bid >> 8;
        int pix = ((bid & 255) << 8) + threadIdx.x;

        int code = codes[(b << 16) + pix];
        int lv = code & 3;
        int am = code >> 2;

        float slab = 0.0f, spred = 0.0f;
        #pragma unroll
        for (int c = 0; c < 3; ++c) {
            int ml = b * 3 + c;
            float dl = ldc(&dbuf[(((size_t)ml) << 16) + pix]);
            slab += sqrtf(dl) * inv[ml];
            float dp = ldc(&dbuf[(((size_t)(ml + 12)) << 16) + pix]);
            spred += sqrtf(dp) * inv[ml + 12];
        }

        float dot = spred * slab + ((am == lv) ? 1.0f : 0.0f);
        float na = sqrtf(spred * spred + 1.0f);
        float nb = sqrtf(slab * slab + 1.0f);
        float sim = dot / (fmaxf(na, 1e-8f) * fmaxf(nb, 1e-8f));

        unsigned long long fg = __ballot(lv > 0);

        #pragma unroll
        for (int off = 32; off; off >>= 1)
            sim += __shfl_down(sim, off, 64);
        if ((threadIdx.x & 63) == 0) {
            wsum[threadIdx.x >> 6] = sim;
            wfg[threadIdx.x >> 6] = (fg != 0ULL) ? 1 : 0;
        }
        __syncthreads();
        if (threadIdx.x == 0) {
            stc(&psum[bid], wsum[0] + wsum[1] + wsum[2] + wsum[3]);
            sti(&pfg[bid], wfg[0] | wfg[1] | wfg[2] | wfg[3]);
        }
    }

    // ------------------------------------------------------------------
    // Phase 4: winner election (last block to arrive, no polling). Winner
    // block reduces psum/pfg in EXACTLY k_finalize's order (bit-exact).
    // ------------------------------------------------------------------
    __syncthreads();
    if (threadIdx.x == 0) {
        asm volatile("s_waitcnt vmcnt(0)" ::: "memory");
        int w = 0;
        int r = faddi(&c3[(bid & 63) * CSTR]);
        if (r == 15) {
            int r2 = faddi(&fl->super3);
            w = (r2 == NCELL - 1);     // last cell to complete -> all data at L3
        }
        iswin = w;
    }
    __syncthreads();
    if (!iswin) return;

    {
        int t = threadIdx.x;
        int b = t >> 6, l = t & 63;
        int base = (b << 8) + l;
        float s = ldc(&psum[base]) + ldc(&psum[base + 64]) +
                  ldc(&psum[base + 128]) + ldc(&psum[base + 192]);
        int f = ldi(&pfg[base]) | ldi(&pfg[base + 64]) |
                ldi(&pfg[base + 128]) | ldi(&pfg[base + 192]);
        #pragma unroll
        for (int off = 32; off; off >>= 1) {
            s += __shfl_down(s, off, 64);
            f |= __shfl_down(f, off, 64);
        }
        if (l == 0) { bsum[b] = s; bfg[b] = f; }
        __syncthreads();
        if (t == 0) {
            float loss = 0.0f;
            for (int bb = 0; bb < BB; ++bb) {
                float lb = 1.0f - bsum[bb] * (1.0f / (float)HW);
                if (bfg[bb]) loss += lb;
            }
            loss *= (1.0f / (float)BB);
            if (isnan(loss)) loss = 0.0f;
            else if (isinf(loss)) loss = (loss > 0.0f) ? 1.0f : 0.0f;
            out[0] = loss;
        }
    }
}

extern "C" void kernel_launch(void* const* d_in, const int* in_sizes, int n_in,
                              void* d_out, int out_size, void* d_ws, size_t ws_size,
                              hipStream_t stream) {
    (void)in_sizes; (void)n_in; (void)out_size; (void)ws_size;
    const float* pred = (const float*)d_in[0];   // [4,3,256,256] f32
    const int*   lab  = (const int*)d_in[1];     // [4,256,256] i32

    char* wsb = (char*)d_ws;
    float* dbuf   = (float*)wsb;                                  // 6 MB
    size_t off    = (size_t)NM * HW * sizeof(float);
    float* blkmax = (float*)(wsb + off);          off += 768 * sizeof(float);
    float* psum   = (float*)(wsb + off);          off += 1024 * sizeof(float);
    int*   pfg    = (int*)  (wsb + off);          off += 1024 * sizeof(int);
    unsigned char* codes = (unsigned char*)(wsb + off);           // 256 KB
    off += (size_t)BB * HW;
    Flags* fl = (Flags*)(wsb + off);                              // ~25 KB

    // Two dispatches: tiny flag-zero, then one fused kernel (1024 blocks
    // co-resident, counting-only barriers, L3-coherent dataflow).
    k_zero<<<1,    256, 0, stream>>>(fl);
    fused <<<NBLK, 256, 0, stream>>>(pred, lab, dbuf, blkmax, psum, pfg,
                                     codes, fl, (float*)d_out);
}

// Round 3
// 85.007 us; speedup vs baseline: 2.3255x; 1.0660x over previous
//
#include <hip/hip_runtime.h>

// Problem constants
#define HH 256
#define WW 256
#define BB 4
#define CC 3
#define HW 65536          // H*W
#define NM 24             // 2*B*C masks (0..11 lab, 12..23 pred)
#define NBLK 1024         // 4 blocks/CU x 256 CUs, all co-resident
#define BIGF 1e9f
#define LIMITF 331776.0f  // 576*576
#define EPSF 1e-5f

// Barrier magics: non-byte-repeating (harness poison fill is a repeated
// byte pattern and can never collide with these).
#define MAGIC2 0x2C8F66EE
#define MAGIC3 0x3D9A77EF

// R6: grid.sync ~90us. R10: __threadfence barrier = L2 wb/inv walk, ~65us
// each. R11 (R2): counting barrier fine (~3us) but making ALL cross-block
// traffic L3-coherent scalar cost ~15us (phase-2 staging: 2048 scalar
// L2-bypass loads/block vs 512 float4 L2 hits).
// R12: hybrid. ONE kernel boundary after rowpass (free coherence for the
// latency-critical colpass staging -> normal float4 loads again). ONE
// in-kernel magic-slot barrier between colpass and final; only colpass
// OUTPUTS (dbuf in-place, blkmax, psum/pfg) go through the coherent point
// (relaxed agent-scope atomics -> globally visible once vmcnt retires, the
// cross-XCD atomicAdd machinery, learn_hip m20). Counter-free protocol:
// arrive slot per block (block0 is the unique reader and resets it), go
// slot per block (its block is the unique reader and resets it) -> correct
// whether or not the harness re-poisons ws between iterations, no init
// dispatch needed. Dispatches: fill + 2 (was fill + 4 in R0).

#define GSTR 8            // go-slot stride in ints (32 B)

struct Flags {
    int arr2[NBLK];       // colpass-done arrive slots (reader: block0)
    int go2[NBLK * GSTR]; // barrier release slots (reader: own block)
    int arr3[NBLK];       // final-done arrive slots (reader: block0)
};

__device__ __forceinline__ float ldc(const float* p) {   // coherent load (L3)
    return __hip_atomic_load((float*)p, __ATOMIC_RELAXED, __HIP_MEMORY_SCOPE_AGENT);
}
__device__ __forceinline__ void stc(float* p, float v) { // coherent store (L3)
    __hip_atomic_store(p, v, __ATOMIC_RELAXED, __HIP_MEMORY_SCOPE_AGENT);
}
__device__ __forceinline__ int ldi(const int* p) {
    return __hip_atomic_load((int*)p, __ATOMIC_RELAXED, __HIP_MEMORY_SCOPE_AGENT);
}
__device__ __forceinline__ void sti(int* p, int v) {
    __hip_atomic_store(p, v, __ATOMIC_RELAXED, __HIP_MEMORY_SCOPE_AGENT);
}

// ---------------------------------------------------------------------------
// Dispatch A: row-wise squared distance to nearest zero, all 6 masks of one
// (batch,row) per block, + per-pixel code byte. Identical math to the proven
// R0 k_rowpass. Normal stores: the kernel boundary makes them visible to B.
// grid: 1024 blocks (b,row), 256 threads (col).
// ---------------------------------------------------------------------------
__global__ __launch_bounds__(256) void k_rowpass(const float* __restrict__ pred,
                                                 const int* __restrict__ lab,
                                                 float* __restrict__ dbuf,
                                                 unsigned char* __restrict__ codes) {
    int blk = blockIdx.x;
    int b = blk >> 8;
    int i = blk & 255;
    int j = threadIdx.x;

    int lv = lab[(b << 16) + (i << 8) + j];
    const float* pb = pred + (((size_t)(b * 3)) << 16) + (i << 8) + j;
    float p0 = pb[0];
    float p1 = pb[(size_t)1 << 16];
    float p2 = pb[(size_t)2 << 16];
    int am = 0; float v = p0;
    if (p1 > v) { am = 1; v = p1; }
    if (p2 > v) { am = 2; }

    codes[(b << 16) + (i << 8) + j] = (unsigned char)(lv | (am << 2));

    __shared__ unsigned long long zm[6][4];
    int w = threadIdx.x >> 6;
    #pragma unroll
    for (int c = 0; c < 3; ++c) {
        unsigned long long zl = __ballot(lv != c);
        unsigned long long zp = __ballot(am != c);
        if ((threadIdx.x & 63) == 0) { zm[c][w] = zl; zm[3 + c][w] = zp; }
    }
    __syncthreads();

    #pragma unroll
    for (int t = 0; t < 6; ++t) {
        int bestd = 512;  // sentinel > any possible distance (<=255)
        #pragma unroll
        for (int w2 = 0; w2 < 4; ++w2) {
            unsigned long long z = zm[t][w2];
            int base = w2 << 6;
            int rel = j - base;
            unsigned long long mle;   // bits at positions <= rel
            if (rel >= 63)      mle = ~0ULL;
            else if (rel < 0)   mle = 0ULL;
            else                mle = (2ULL << rel) - 1ULL;
            unsigned long long zl = z & mle;
            if (zl) {
                int p = base + 63 - __clzll(zl);
                int d = j - p;
                if (d < bestd) bestd = d;
            }
            unsigned long long zr = z & ~mle;
            if (zr) {
                int p = base + __ffsll(zr) - 1;
                int d = p - j;
                if (d < bestd) bestd = d;
            }
        }
        float d1 = (bestd >= 512) ? BIGF : (float)(bestd * bestd);
        int c = (t < 3) ? t : (t - 3);
        int m = ((t < 3) ? 0 : 12) + b * 3 + c;
        dbuf[(((size_t)m) << 16) + (i << 8) + j] = d1;
    }
}

// ---------------------------------------------------------------------------
// Dispatch B: colpass -> magic barrier -> final -> block0 finalize.
// grid: 1024 blocks, 256 threads, all co-resident (LDS 11.7KB, 4 blk/CU).
// ---------------------------------------------------------------------------
__global__ __launch_bounds__(256, 4) void k_rest(
        const unsigned char* __restrict__ codes, const int* __restrict__ lab,
        float* __restrict__ dbuf, float* __restrict__ blkmax,
        float* __restrict__ psum, int* __restrict__ pfg,
        Flags* __restrict__ fl, float* __restrict__ out) {
    __shared__ float tile[320 * 9];   // rows 0..319 = k -32..287, stride 9
    __shared__ float wmax[4];
    __shared__ float inv[NM];
    __shared__ float wsum[4];
    __shared__ int   wfg[4];
    __shared__ float bsum[4];
    __shared__ int   bfg[4];

    const int bid = blockIdx.x;

    // ------------------------------------------------------------------
    // Phase 1: column min-plus, wave-uniform exact window. Identical math
    // to the proven R0 k_colpass. Staging loads NORMAL float4 (rowpass
    // data crossed the kernel boundary -> coherent + L2/L3-warm). Result
    // stores coherent (read cross-block after the in-kernel barrier).
    // Blocks >= 768 skip to the barrier.
    // ------------------------------------------------------------------
    if (bid < NM * 32) {
        int m = bid >> 5;
        int j0 = (bid & 31) << 3;
        float* base = dbuf + (((size_t)m) << 16);

        {   // guard rows (k=-32..-1, 256..287) = BIG
            int t = threadIdx.x;
            int gr = t >> 3, gc = t & 7;
            tile[gr * 9 + gc] = BIGF;
            tile[(288 + gr) * 9 + gc] = BIGF;
        }
        #pragma unroll
        for (int it = 0; it < 2; ++it) {
            int f = (it << 8) + threadIdx.x;   // float4 index 0..511
            int row = f >> 1, half = f & 1;
            float4 v4 = *(const float4*)(base + (row << 8) + j0 + (half << 2));
            int lb = (row + 32) * 9 + (half << 2);
            tile[lb + 0] = v4.x; tile[lb + 1] = v4.y;
            tile[lb + 2] = v4.z; tile[lb + 3] = v4.w;
        }
        __syncthreads();

        int jj = threadIdx.x & 7;
        int ib = threadIdx.x >> 3;   // 0..31

        float acc[8];
        float dmax = 0.0f;
        #pragma unroll
        for (int r = 0; r < 8; ++r) {
            acc[r] = tile[(ib + (r << 5) + 32) * 9 + jj];   // k=i candidate
            dmax = fmaxf(dmax, acc[r]);
        }
        #pragma unroll
        for (int off = 32; off; off >>= 1)
            dmax = fmaxf(dmax, __shfl_xor(dmax, off, 64));
        int Rmax = (int)sqrtf(dmax) + 1;
        if (Rmax > 255) Rmax = 255;

        if (Rmax <= 32) {
            // Fast path: guards cover k=i+o fully; dk^2 = o^2 wave-scalar.
            for (int o = -Rmax; o <= Rmax; ++o) {
                float o2 = (float)(o * o);
                #pragma unroll
                for (int r = 0; r < 8; ++r)
                    acc[r] = fminf(acc[r], o2 + tile[(ib + (r << 5) + 32 + o) * 9 + jj]);
            }
        } else {
            // Slow path (BIG rows in wave): clamped candidates, exact.
            for (int o = -Rmax; o <= Rmax; ++o) {
                #pragma unroll
                for (int r = 0; r < 8; ++r) {
                    int i = ib + (r << 5);
                    int k = i + o;
                    k = (k < 0) ? 0 : ((k > 255) ? 255 : k);
                    float dk = (float)(k - i);
                    acc[r] = fminf(acc[r], fmaf(dk, dk, tile[(k + 32) * 9 + jj]));
                }
            }
        }

        float lmax = 0.0f;
        #pragma unroll
        for (int r = 0; r < 8; ++r) {
            int i = ib + (r << 5);
            stc(&base[(i << 8) + j0 + jj], acc[r]);   // coherent: read post-barrier
            lmax = fmaxf(lmax, acc[r]);
        }
        #pragma unroll
        for (int off = 32; off; off >>= 1)
            lmax = fmaxf(lmax, __shfl_down(lmax, off, 64));
        if ((threadIdx.x & 63) == 0) wmax[threadIdx.x >> 6] = lmax;
        __syncthreads();
        if (threadIdx.x == 0)
            stc(&blkmax[bid], fmaxf(fmaxf(wmax[0], wmax[1]), fmaxf(wmax[2], wmax[3])));
    }

    // ------------------------------------------------------------------
    // Grid barrier (counter-free, no cache maintenance). Arrive: MAGIC2
    // into own slot after vmcnt drain (stc data then at coherent point).
    // Block0 polls all 1024 slots (4/thread), resets each to 0 (sole
    // reader), then broadcasts MAGIC2 to per-block go slots; each block
    // polls only ITS slot and resets it (sole reader). Self-cleaning under
    // both re-poison and no-re-poison harness semantics.
    // ------------------------------------------------------------------
    __syncthreads();
    if (threadIdx.x == 0) {
        asm volatile("s_waitcnt vmcnt(0)" ::: "memory");
        sti(&fl->arr2[bid], MAGIC2);
    }
    if (bid == 0) {
        int i0 = threadIdx.x << 2;
        #pragma unroll
        for (int k = 0; k < 4; ++k) {
            while (ldi(&fl->arr2[i0 + k]) != MAGIC2) __builtin_amdgcn_s_sleep(1);
            sti(&fl->arr2[i0 + k], 0);
        }
        __syncthreads();
        #pragma unroll
        for (int k = 0; k < 4; ++k)
            sti(&fl->go2[(i0 + k) * GSTR], MAGIC2);
    } else if (threadIdx.x == 0) {
        while (ldi(&fl->go2[bid * GSTR]) != MAGIC2) __builtin_amdgcn_s_sleep(1);
        sti(&fl->go2[bid * GSTR], 0);
    }
    __syncthreads();

    // ------------------------------------------------------------------
    // Phase 2: per-pixel cosine sim -> per-block partials. Identical math
    // to the proven R0 k_final. dbuf/blkmax reads coherent (coalesced
    // scalar); codes/lab read normal (kernel boundary).
    // ------------------------------------------------------------------
    {
        if (threadIdx.x < NM) {
            const float* bm = blkmax + (threadIdx.x << 5);
            float v = 0.0f;
            #pragma unroll
            for (int s = 0; s < 32; ++s) v = fmaxf(v, ldc(&bm[s]));
            inv[threadIdx.x] = 1.0f / (fminf(sqrtf(v), LIMITF) + EPSF);
        }
        __syncthreads();

        int b = bid >> 8;
        int pix = ((bid & 255) << 8) + threadIdx.x;

        int code = codes[(b << 16) + pix];
        int lv = code & 3;
        int am = code >> 2;

        float slab = 0.0f, spred = 0.0f;
        #pragma unroll
        for (int c = 0; c < 3; ++c) {
            int ml = b * 3 + c;
            float dl = ldc(&dbuf[(((size_t)ml) << 16) + pix]);
            slab += sqrtf(dl) * inv[ml];
            float dp = ldc(&dbuf[(((size_t)(ml + 12)) << 16) + pix]);
            spred += sqrtf(dp) * inv[ml + 12];
        }

        float dot = spred * slab + ((am == lv) ? 1.0f : 0.0f);
        float na = sqrtf(spred * spred + 1.0f);
        float nb = sqrtf(slab * slab + 1.0f);
        float sim = dot / (fmaxf(na, 1e-8f) * fmaxf(nb, 1e-8f));

        unsigned long long fg = __ballot(lv > 0);

        #pragma unroll
        for (int off = 32; off; off >>= 1)
            sim += __shfl_down(sim, off, 64);
        if ((threadIdx.x & 63) == 0) {
            wsum[threadIdx.x >> 6] = sim;
            wfg[threadIdx.x >> 6] = (fg != 0ULL) ? 1 : 0;
        }
        __syncthreads();
        if (threadIdx.x == 0) {
            stc(&psum[bid], wsum[0] + wsum[1] + wsum[2] + wsum[3]);
            sti(&pfg[bid], wfg[0] | wfg[1] | wfg[2] | wfg[3]);
            asm volatile("s_waitcnt vmcnt(0)" ::: "memory");
            sti(&fl->arr3[bid], MAGIC3);
        }
    }

    if (bid != 0) return;

    // ------------------------------------------------------------------
    // Phase 3 (block0): wait for all partials, reduce in EXACTLY the
    // k_finalize order (bit-exact), write loss. Resets arr3 (sole reader).
    // ------------------------------------------------------------------
    {
        int i0 = threadIdx.x << 2;
        #pragma unroll
        for (int k = 0; k < 4; ++k) {
            while (ldi(&fl->arr3[i0 + k]) != MAGIC3) __builtin_amdgcn_s_sleep(1);
            sti(&fl->arr3[i0 + k], 0);
        }
        __syncthreads();

        int t = threadIdx.x;
        int b = t >> 6, l = t & 63;
        int base = (b << 8) + l;
        float s = ldc(&psum[base]) + ldc(&psum[base + 64]) +
                  ldc(&psum[base + 128]) + ldc(&psum[base + 192]);
        int f = ldi(&pfg[base]) | ldi(&pfg[base + 64]) |
                ldi(&pfg[base + 128]) | ldi(&pfg[base + 192]);
        #pragma unroll
        for (int off = 32; off; off >>= 1) {
            s += __shfl_down(s, off, 64);
            f |= __shfl_down(f, off, 64);
        }
        if (l == 0) { bsum[b] = s; bfg[b] = f; }
        __syncthreads();
        if (t == 0) {
            float loss = 0.0f;
            for (int bb = 0; bb < BB; ++bb) {
                float lb = 1.0f - bsum[bb] * (1.0f / (float)HW);
                if (bfg[bb]) loss += lb;
            }
            loss *= (1.0f / (float)BB);
            if (isnan(loss)) loss = 0.0f;
            else if (isinf(loss)) loss = (loss > 0.0f) ? 1.0f : 0.0f;
            out[0] = loss;
        }
    }
}

extern "C" void kernel_launch(void* const* d_in, const int* in_sizes, int n_in,
                              void* d_out, int out_size, void* d_ws, size_t ws_size,
                              hipStream_t stream) {
    (void)in_sizes; (void)n_in; (void)out_size; (void)ws_size;
    const float* pred = (const float*)d_in[0];   // [4,3,256,256] f32
    const int*   lab  = (const int*)d_in[1];     // [4,256,256] i32

    char* wsb = (char*)d_ws;
    float* dbuf   = (float*)wsb;                                  // 6 MB
    size_t off    = (size_t)NM * HW * sizeof(float);
    float* blkmax = (float*)(wsb + off);          off += 768 * sizeof(float);
    float* psum   = (float*)(wsb + off);          off += 1024 * sizeof(float);
    int*   pfg    = (int*)  (wsb + off);          off += 1024 * sizeof(int);
    unsigned char* codes = (unsigned char*)(wsb + off);           // 256 KB
    off += (size_t)BB * HW;
    Flags* fl = (Flags*)(wsb + off);                              // 40 KB

    // Two dispatches: rowpass, then colpass+barrier+final+finalize.
    k_rowpass<<<NBLK, 256, 0, stream>>>(pred, lab, dbuf, codes);
    k_rest   <<<NBLK, 256, 0, stream>>>(codes, lab, dbuf, blkmax, psum, pfg,
                                        fl, (float*)d_out);
}

// Round 4
// 84.060 us; speedup vs baseline: 2.3517x; 1.0113x over previous
//
#include <hip/hip_runtime.h>

// Problem constants
#define HH 256
#define WW 256
#define BB 4
#define CC 3
#define HW 65536          // H*W
#define NM 24             // 2*B*C masks (0..11 lab, 12..23 pred)
#define NBLK 1024
#define BIGF 1e9f
#define LIMITF 331776.0f  // 576*576
#define EPSF 1e-5f

// Non-byte-repeating magic (harness poison is a repeated byte pattern).
#define MAGIC3 0x3D9A77EF

// Sync ledger (dur - 41us fill): R0 4-launch 39.5 | R2 fused all-coherent
// 49.2 | R3 2-launch + mediated grid barrier 43.7. Full in-kernel barriers
// (release fan-out = ~3 L3 round trips, 6-10us) always lose to graph-node
// transitions (~3-4us). R13: keep kernel boundaries for row->col->final;
// fuse ONLY final+finalize via a one-way producer wait (arrive flag after
// vmcnt drain; block0 polls directly -- no mediation, no fan-out). Only
// psum/pfg (2 dwords/block) travel the coherent path; all hot-loop memory
// ops are normal (boundary-coherent). Flag slots are self-cleaning (block0
// is the sole reader and zeroes them), so correctness holds whether or not
// the harness re-poisons the workspace. Dispatches: fill + 3 (was + 4).

__device__ __forceinline__ float ldc(const float* p) {   // coherent load (L3)
    return __hip_atomic_load((float*)p, __ATOMIC_RELAXED, __HIP_MEMORY_SCOPE_AGENT);
}
__device__ __forceinline__ void stc(float* p, float v) { // coherent store (L3)
    __hip_atomic_store(p, v, __ATOMIC_RELAXED, __HIP_MEMORY_SCOPE_AGENT);
}
__device__ __forceinline__ int ldi(const int* p) {
    return __hip_atomic_load((int*)p, __ATOMIC_RELAXED, __HIP_MEMORY_SCOPE_AGENT);
}
__device__ __forceinline__ void sti(int* p, int v) {
    __hip_atomic_store(p, v, __ATOMIC_RELAXED, __HIP_MEMORY_SCOPE_AGENT);
}

// ---------------------------------------------------------------------------
// Pass 1: row-wise squared distance to nearest zero, all 6 masks of one
// (batch,row) per block + per-pixel code byte. Byte-identical to R0.
// grid: 4*256 blocks (b,row), 256 threads (col).
// ---------------------------------------------------------------------------
__global__ __launch_bounds__(256) void k_rowpass(const float* __restrict__ pred,
                                                 const int* __restrict__ lab,
                                                 float* __restrict__ dbuf,
                                                 unsigned char* __restrict__ codes) {
    int blk = blockIdx.x;
    int b = blk >> 8;
    int i = blk & 255;
    int j = threadIdx.x;

    int lv = lab[(b << 16) + (i << 8) + j];
    const float* pb = pred + (((size_t)(b * 3)) << 16) + (i << 8) + j;
    float p0 = pb[0];
    float p1 = pb[(size_t)1 << 16];
    float p2 = pb[(size_t)2 << 16];
    int am = 0; float v = p0;
    if (p1 > v) { am = 1; v = p1; }
    if (p2 > v) { am = 2; }

    codes[(b << 16) + (i << 8) + j] = (unsigned char)(lv | (am << 2));

    __shared__ unsigned long long zm[6][4];
    int w = threadIdx.x >> 6;
    #pragma unroll
    for (int c = 0; c < 3; ++c) {
        unsigned long long zl = __ballot(lv != c);
        unsigned long long zp = __ballot(am != c);
        if ((threadIdx.x & 63) == 0) { zm[c][w] = zl; zm[3 + c][w] = zp; }
    }
    __syncthreads();

    #pragma unroll
    for (int t = 0; t < 6; ++t) {
        int bestd = 512;  // sentinel > any possible distance (<=255)
        #pragma unroll
        for (int w2 = 0; w2 < 4; ++w2) {
            unsigned long long z = zm[t][w2];
            int base = w2 << 6;
            int rel = j - base;
            unsigned long long mle;   // bits at positions <= rel
            if (rel >= 63)      mle = ~0ULL;
            else if (rel < 0)   mle = 0ULL;
            else                mle = (2ULL << rel) - 1ULL;
            unsigned long long zl = z & mle;
            if (zl) {
                int p = base + 63 - __clzll(zl);
                int d = j - p;
                if (d < bestd) bestd = d;
            }
            unsigned long long zr = z & ~mle;
            if (zr) {
                int p = base + __ffsll(zr) - 1;
                int d = p - j;
                if (d < bestd) bestd = d;
            }
        }
        float d1 = (bestd >= 512) ? BIGF : (float)(bestd * bestd);
        int c = (t < 3) ? t : (t - 3);
        int m = ((t < 3) ? 0 : 12) + b * 3 + c;
        dbuf[(((size_t)m) << 16) + (i << 8) + j] = d1;
    }
}

// ---------------------------------------------------------------------------
// Pass 2: column min-plus, wave-uniform exact window. Byte-identical to R0
// (normal float4 staging loads, normal stores — boundary coherence).
// grid: 24*32 blocks, 256 threads.
// ---------------------------------------------------------------------------
__global__ __launch_bounds__(256) void k_colpass(float* __restrict__ dbuf,
                                                 float* __restrict__ blkmax) {
    int blk = blockIdx.x;
    int m = blk >> 5;
    int j0 = (blk & 31) << 3;
    __shared__ float tile[320 * 9];   // rows 0..319 = k -32..287, stride 9
    float* base = dbuf + (((size_t)m) << 16);

    {   // guard rows (k=-32..-1, 256..287) = BIG
        int t = threadIdx.x;
        int gr = t >> 3, gc = t & 7;
        tile[gr * 9 + gc] = BIGF;
        tile[(288 + gr) * 9 + gc] = BIGF;
    }
    #pragma unroll
    for (int it = 0; it < 2; ++it) {
        int f = (it << 8) + threadIdx.x;   // float4 index 0..511
        int row = f >> 1, half = f & 1;
        float4 v4 = *(const float4*)(base + (row << 8) + j0 + (half << 2));
        int lb = (row + 32) * 9 + (half << 2);
        tile[lb + 0] = v4.x; tile[lb + 1] = v4.y;
        tile[lb + 2] = v4.z; tile[lb + 3] = v4.w;
    }
    __syncthreads();

    int jj = threadIdx.x & 7;
    int ib = threadIdx.x >> 3;   // 0..31

    float acc[8];
    float dmax = 0.0f;
    #pragma unroll
    for (int r = 0; r < 8; ++r) {
        acc[r] = tile[(ib + (r << 5) + 32) * 9 + jj];   // k=i candidate
        dmax = fmaxf(dmax, acc[r]);
    }
    #pragma unroll
    for (int off = 32; off; off >>= 1)
        dmax = fmaxf(dmax, __shfl_xor(dmax, off, 64));
    int Rmax = (int)sqrtf(dmax) + 1;
    if (Rmax > 255) Rmax = 255;

    if (Rmax <= 32) {
        // Fast path: guards cover k=i+o fully; dk^2 = o^2 wave-scalar.
        for (int o = -Rmax; o <= Rmax; ++o) {
            float o2 = (float)(o * o);
            #pragma unroll
            for (int r = 0; r < 8; ++r)
                acc[r] = fminf(acc[r], o2 + tile[(ib + (r << 5) + 32 + o) * 9 + jj]);
        }
    } else {
        // Slow path (BIG rows in wave): clamped candidates, exact.
        for (int o = -Rmax; o <= Rmax; ++o) {
            #pragma unroll
            for (int r = 0; r < 8; ++r) {
                int i = ib + (r << 5);
                int k = i + o;
                k = (k < 0) ? 0 : ((k > 255) ? 255 : k);
                float dk = (float)(k - i);
                acc[r] = fminf(acc[r], fmaf(dk, dk, tile[(k + 32) * 9 + jj]));
            }
        }
    }

    float lmax = 0.0f;
    #pragma unroll
    for (int r = 0; r < 8; ++r) {
        int i = ib + (r << 5);
        base[(i << 8) + j0 + jj] = acc[r];
        lmax = fmaxf(lmax, acc[r]);
    }

    #pragma unroll
    for (int off = 32; off; off >>= 1)
        lmax = fmaxf(lmax, __shfl_down(lmax, off, 64));
    __shared__ float wmax[4];
    if ((threadIdx.x & 63) == 0) wmax[threadIdx.x >> 6] = lmax;
    __syncthreads();
    if (threadIdx.x == 0)
        blkmax[blk] = fmaxf(fmaxf(wmax[0], wmax[1]), fmaxf(wmax[2], wmax[3]));
}

// ---------------------------------------------------------------------------
// Pass 3: per-pixel cosine sim -> per-block partials, then block0 performs
// the finalize reduction after a one-way wait on 1024 arrive flags (direct
// polling, no mediation/fan-out -- the cheap sub-protocol from R2/R3).
// Partial-sum math and reduction order byte-identical to R0 k_final +
// k_finalize. grid: 1024 blocks x 256.
// ---------------------------------------------------------------------------
__global__ __launch_bounds__(256) void k_final(const unsigned char* __restrict__ codes,
                                               const float* __restrict__ dbuf,
                                               const float* __restrict__ blkmax,
                                               float* __restrict__ psum,
                                               int* __restrict__ pfg,
                                               int* __restrict__ arr3,
                                               float* __restrict__ out) {
    __shared__ float inv[NM];
    if (threadIdx.x < NM) {
        const float* bm = blkmax + (threadIdx.x << 5);
        float v = 0.0f;
        #pragma unroll
        for (int s = 0; s < 32; ++s) v = fmaxf(v, bm[s]);
        inv[threadIdx.x] = 1.0f / (fminf(sqrtf(v), LIMITF) + EPSF);
    }
    __syncthreads();

    int b = blockIdx.x >> 8;                         // uniform per block
    int pix = ((blockIdx.x & 255) << 8) + threadIdx.x;

    int code = codes[(b << 16) + pix];
    int lv = code & 3;
    int am = code >> 2;

    float slab = 0.0f, spred = 0.0f;
    #pragma unroll
    for (int c = 0; c < 3; ++c) {
        int ml = b * 3 + c;
        float dl = dbuf[(((size_t)ml) << 16) + pix];
        slab += sqrtf(dl) * inv[ml];
        float dp = dbuf[(((size_t)(ml + 12)) << 16) + pix];
        spred += sqrtf(dp) * inv[ml + 12];
    }

    float dot = spred * slab + ((am == lv) ? 1.0f : 0.0f);
    float na = sqrtf(spred * spred + 1.0f);
    float nb = sqrtf(slab * slab + 1.0f);
    float sim = dot / (fmaxf(na, 1e-8f) * fmaxf(nb, 1e-8f));

    unsigned long long fg = __ballot(lv > 0);

    #pragma unroll
    for (int off = 32; off; off >>= 1)
        sim += __shfl_down(sim, off, 64);
    __shared__ float wsum[4];
    __shared__ int wfg[4];
    if ((threadIdx.x & 63) == 0) {
        wsum[threadIdx.x >> 6] = sim;
        wfg[threadIdx.x >> 6] = (fg != 0ULL) ? 1 : 0;
    }
    __syncthreads();
    if (threadIdx.x == 0) {
        // Coherent partials (L3) + vmcnt drain, then arrive flag: a consumer
        // that sees MAGIC3 is guaranteed to see psum/pfg at the coherent pt.
        stc(&psum[blockIdx.x], wsum[0] + wsum[1] + wsum[2] + wsum[3]);
        sti(&pfg[blockIdx.x], wfg[0] | wfg[1] | wfg[2] | wfg[3]);
        asm volatile("s_waitcnt vmcnt(0)" ::: "memory");
        sti(&arr3[blockIdx.x], MAGIC3);
    }

    if (blockIdx.x != 0) return;

    // Block0: wait for all partials (direct one-way poll, sole reader ->
    // reset slots), then reduce in EXACTLY the R0 k_finalize order.
    {
        int i0 = threadIdx.x << 2;
        #pragma unroll
        for (int k = 0; k < 4; ++k) {
            while (ldi(&arr3[i0 + k]) != MAGIC3) __builtin_amdgcn_s_sleep(1);
            sti(&arr3[i0 + k], 0);
        }
        __syncthreads();

        int t = threadIdx.x;
        int bb_ = t >> 6, l = t & 63;
        int base = (bb_ << 8) + l;
        float s = ldc(&psum[base]) + ldc(&psum[base + 64]) +
                  ldc(&psum[base + 128]) + ldc(&psum[base + 192]);
        int f = ldi(&pfg[base]) | ldi(&pfg[base + 64]) |
                ldi(&pfg[base + 128]) | ldi(&pfg[base + 192]);
        #pragma unroll
        for (int off = 32; off; off >>= 1) {
            s += __shfl_down(s, off, 64);
            f |= __shfl_down(f, off, 64);
        }
        __shared__ float bsum[4];
        __shared__ int bfg[4];
        if (l == 0) { bsum[bb_] = s; bfg[bb_] = f; }
        __syncthreads();
        if (t == 0) {
            float loss = 0.0f;
            for (int bb = 0; bb < BB; ++bb) {
                float lb = 1.0f - bsum[bb] * (1.0f / (float)HW);
                if (bfg[bb]) loss += lb;
            }
            loss *= (1.0f / (float)BB);
            if (isnan(loss)) loss = 0.0f;
            else if (isinf(loss)) loss = (loss > 0.0f) ? 1.0f : 0.0f;
            out[0] = loss;
        }
    }
}

extern "C" void kernel_launch(void* const* d_in, const int* in_sizes, int n_in,
                              void* d_out, int out_size, void* d_ws, size_t ws_size,
                              hipStream_t stream) {
    (void)in_sizes; (void)n_in; (void)out_size; (void)ws_size;
    const float* pred = (const float*)d_in[0];   // [4,3,256,256] f32
    const int*   lab  = (const int*)d_in[1];     // [4,256,256] i32

    char* wsb = (char*)d_ws;
    float* dbuf   = (float*)wsb;                                  // 6 MB
    size_t off    = (size_t)NM * HW * sizeof(float);
    float* blkmax = (float*)(wsb + off);          off += 768 * sizeof(float);
    float* psum   = (float*)(wsb + off);          off += 1024 * sizeof(float);
    int*   pfg    = (int*)  (wsb + off);          off += 1024 * sizeof(int);
    unsigned char* codes = (unsigned char*)(wsb + off);           // 256 KB
    off += (size_t)BB * HW;
    int* arr3 = (int*)(wsb + off);                                // 4 KB

    // Three dispatches (was four): finalize folded into k_final via a
    // one-way producer wait. Every scratch word is written before read.
    k_rowpass<<<NBLK,     256, 0, stream>>>(pred, lab, dbuf, codes);
    k_colpass<<<NM * 32,  256, 0, stream>>>(dbuf, blkmax);
    k_final  <<<NBLK,     256, 0, stream>>>(codes, dbuf, blkmax, psum, pfg,
                                            arr3, (float*)d_out);
}

// Round 5
// 74.685 us; speedup vs baseline: 2.6469x; 1.1255x over previous
//
#include <hip/hip_runtime.h>

// Problem constants
#define HH 256
#define WW 256
#define BB 4
#define CC 3
#define HW 65536          // H*W
#define NM 24             // 2*B*C masks (0..11 lab, 12..23 pred)
#define NBLK 1024
#define BIGF 1e9f
#define LIMITF 331776.0f  // 576*576
#define EPSF 1e-5f

// Sync ledger (dur_us): R0 4-launch 80.8 | R2 1-launch all-coherent 90.6 |
// R3 2-launch + mediated barrier 85.0 | R4 3-launch + one-way wait 84.1.
// Graph-node transitions are ~1-2us (R3->R4 delta), so EVERY in-kernel wait
// (even one-way polling) loses to a plain kernel boundary: the producer tail
// + L3 round-trip serializes on the kernel's critical path, while a boundary
// overlaps drain with next-node dispatch. R14: revert to the proven 4-launch
// topology and instead cut DATA: rowpass no longer writes 6MB of d1 --- it
// emits 192KB of per-row zero-bitmaps; colpass recomputes d1 inline from an
// 8KB LDS bitmap (same clz/ffs scan, relocated, no duplicated work,
// bit-identical floats). Saves the 12MB d1 round-trip entirely.

// ---------------------------------------------------------------------------
// Pass 1: per-(batch,row) zero-pixel bitmaps for all 6 masks + per-pixel
// code byte (lab | argmax<<2). grid: 4*256 blocks, 256 threads (col).
// bits layout: [m][row][4] u64 --- bit k of word w = column w*64+k.
// ---------------------------------------------------------------------------
__global__ __launch_bounds__(256) void k_rowpass(const float* __restrict__ pred,
                                                 const int* __restrict__ lab,
                                                 unsigned long long* __restrict__ bits,
                                                 unsigned char* __restrict__ codes) {
    int blk = blockIdx.x;
    int b = blk >> 8;
    int i = blk & 255;
    int j = threadIdx.x;

    int lv = lab[(b << 16) + (i << 8) + j];
    const float* pb = pred + (((size_t)(b * 3)) << 16) + (i << 8) + j;
    float p0 = pb[0];
    float p1 = pb[(size_t)1 << 16];
    float p2 = pb[(size_t)2 << 16];
    int am = 0; float v = p0;
    if (p1 > v) { am = 1; v = p1; }
    if (p2 > v) { am = 2; }

    codes[(b << 16) + (i << 8) + j] = (unsigned char)(lv | (am << 2));

    __shared__ unsigned long long zm[6][4];
    int w = threadIdx.x >> 6;
    #pragma unroll
    for (int c = 0; c < 3; ++c) {
        unsigned long long zl = __ballot(lv != c);
        unsigned long long zp = __ballot(am != c);
        if ((threadIdx.x & 63) == 0) { zm[c][w] = zl; zm[3 + c][w] = zp; }
    }
    __syncthreads();

    // 24 u64 stores: thread t -> mask t>>2, word t&3 (32B contiguous/mask).
    if (threadIdx.x < 24) {
        int t = threadIdx.x >> 2;
        int w2 = threadIdx.x & 3;
        int c = (t < 3) ? t : (t - 3);
        int m = ((t < 3) ? 0 : 12) + b * 3 + c;
        bits[(((size_t)m) << 10) + (i << 2) + w2] = zm[t][w2];
    }
}

// ---------------------------------------------------------------------------
// Pass 2: recompute d1 from the mask bitmap (8KB in LDS), then column
// min-plus d[i,j]=min_k d1[k,j]+(i-k)^2 with the proven wave-uniform exact
// window (fast path Rmax<=32: guards make dk^2 a wave-scalar add,
// bit-identical; slow path: clamped, exact). One block owns 8 FULL columns.
// grid: 24*32 blocks, 256 threads. Writes final distances to dbuf + blkmax.
// ---------------------------------------------------------------------------
__global__ __launch_bounds__(256) void k_colpass(const unsigned long long* __restrict__ bits,
                                                 float* __restrict__ dbuf,
                                                 float* __restrict__ blkmax) {
    int blk = blockIdx.x;
    int m = blk >> 5;
    int j0 = (blk & 31) << 3;
    __shared__ float tile[320 * 9];            // rows 0..319 = k -32..287, stride 9
    __shared__ unsigned long long zb[256][4];  // row bitmaps, 8 KB
    float* base = dbuf + (((size_t)m) << 16);

    {   // stage bitmaps (1024 u64, 4/thread, coalesced) + guard rows = BIG
        const unsigned long long* bm = bits + (((size_t)m) << 10);
        int t = threadIdx.x;
        #pragma unroll
        for (int k = 0; k < 4; ++k) {
            int idx = t + (k << 8);
            zb[idx >> 2][idx & 3] = bm[idx];
        }
        int gr = t >> 3, gc = t & 7;
        tile[gr * 9 + gc] = BIGF;              // k = -32..-1
        tile[(288 + gr) * 9 + gc] = BIGF;      // k = 256..287
    }
    __syncthreads();

    int jj = threadIdx.x & 7;
    int ib = threadIdx.x >> 3;   // 0..31
    int j = j0 + jj;             // this thread's column

    // d1 for own 8 rows from the bitmap --- EXACT rowpass logic, relocated.
    #pragma unroll
    for (int r = 0; r < 8; ++r) {
        int row = ib + (r << 5);
        int bestd = 512;  // sentinel > any possible distance (<=255)
        #pragma unroll
        for (int w2 = 0; w2 < 4; ++w2) {
            unsigned long long z = zb[row][w2];
            int basew = w2 << 6;
            int rel = j - basew;
            unsigned long long mle;   // bits at positions <= rel
            if (rel >= 63)      mle = ~0ULL;
            else if (rel < 0)   mle = 0ULL;
            else                mle = (2ULL << rel) - 1ULL;
            unsigned long long zlo = z & mle;
            if (zlo) {
                int p = basew + 63 - __clzll(zlo);
                int d = j - p;
                if (d < bestd) bestd = d;
            }
            unsigned long long zr = z & ~mle;
            if (zr) {
                int p = basew + __ffsll(zr) - 1;
                int d = p - j;
                if (d < bestd) bestd = d;
            }
        }
        tile[(row + 32) * 9 + jj] = (bestd >= 512) ? BIGF : (float)(bestd * bestd);
    }
    __syncthreads();

    float acc[8];
    float dmax = 0.0f;
    #pragma unroll
    for (int r = 0; r < 8; ++r) {
        acc[r] = tile[(ib + (r << 5) + 32) * 9 + jj];   // k=i candidate
        dmax = fmaxf(dmax, acc[r]);
    }
    #pragma unroll
    for (int off = 32; off; off >>= 1)
        dmax = fmaxf(dmax, __shfl_xor(dmax, off, 64));
    int Rmax = (int)sqrtf(dmax) + 1;
    if (Rmax > 255) Rmax = 255;

    if (Rmax <= 32) {
        // Fast path: guards cover k=i+o fully; dk^2 = o^2 wave-scalar.
        for (int o = -Rmax; o <= Rmax; ++o) {
            float o2 = (float)(o * o);
            #pragma unroll
            for (int r = 0; r < 8; ++r)
                acc[r] = fminf(acc[r], o2 + tile[(ib + (r << 5) + 32 + o) * 9 + jj]);
        }
    } else {
        // Slow path (BIG rows in wave): clamped candidates, exact full logic.
        for (int o = -Rmax; o <= Rmax; ++o) {
            #pragma unroll
            for (int r = 0; r < 8; ++r) {
                int i = ib + (r << 5);
                int k = i + o;
                k = (k < 0) ? 0 : ((k > 255) ? 255 : k);
                float dk = (float)(k - i);
                acc[r] = fminf(acc[r], fmaf(dk, dk, tile[(k + 32) * 9 + jj]));
            }
        }
    }

    float lmax = 0.0f;
    #pragma unroll
    for (int r = 0; r < 8; ++r) {
        int i = ib + (r << 5);
        base[(i << 8) + j0 + jj] = acc[r];
        lmax = fmaxf(lmax, acc[r]);
    }

    #pragma unroll
    for (int off = 32; off; off >>= 1)
        lmax = fmaxf(lmax, __shfl_down(lmax, off, 64));
    __shared__ float wmax[4];
    if ((threadIdx.x & 63) == 0) wmax[threadIdx.x >> 6] = lmax;
    __syncthreads();
    if (threadIdx.x == 0)
        blkmax[blk] = fmaxf(fmaxf(wmax[0], wmax[1]), fmaxf(wmax[2], wmax[3]));
}

// ---------------------------------------------------------------------------
// Pass 3: per-pixel cosine sim -> per-BLOCK partials (byte-identical to R0).
// grid: 1024 blocks x 256 (blocks 256b..256b+255 cover batch b).
// ---------------------------------------------------------------------------
__global__ __launch_bounds__(256) void k_final(const unsigned char* __restrict__ codes,
                                               const float* __restrict__ dbuf,
                                               const float* __restrict__ blkmax,
                                               float* __restrict__ psum,
                                               int* __restrict__ pfg) {
    __shared__ float inv[NM];
    if (threadIdx.x < NM) {
        const float* bm = blkmax + (threadIdx.x << 5);
        float v = 0.0f;
        #pragma unroll
        for (int s = 0; s < 32; ++s) v = fmaxf(v, bm[s]);
        inv[threadIdx.x] = 1.0f / (fminf(sqrtf(v), LIMITF) + EPSF);
    }
    __syncthreads();

    int b = blockIdx.x >> 8;                         // uniform per block
    int pix = ((blockIdx.x & 255) << 8) + threadIdx.x;

    int code = codes[(b << 16) + pix];
    int lv = code & 3;
    int am = code >> 2;

    float slab = 0.0f, spred = 0.0f;
    #pragma unroll
    for (int c = 0; c < 3; ++c) {
        int ml = b * 3 + c;
        float dl = dbuf[(((size_t)ml) << 16) + pix];
        slab += sqrtf(dl) * inv[ml];
        float dp = dbuf[(((size_t)(ml + 12)) << 16) + pix];
        spred += sqrtf(dp) * inv[ml + 12];
    }

    float dot = spred * slab + ((am == lv) ? 1.0f : 0.0f);
    float na = sqrtf(spred * spred + 1.0f);
    float nb = sqrtf(slab * slab + 1.0f);
    float sim = dot / (fmaxf(na, 1e-8f) * fmaxf(nb, 1e-8f));

    unsigned long long fg = __ballot(lv > 0);

    #pragma unroll
    for (int off = 32; off; off >>= 1)
        sim += __shfl_down(sim, off, 64);
    __shared__ float wsum[4];
    __shared__ int wfg[4];
    if ((threadIdx.x & 63) == 0) {
        wsum[threadIdx.x >> 6] = sim;
        wfg[threadIdx.x >> 6] = (fg != 0ULL) ? 1 : 0;
    }
    __syncthreads();
    if (threadIdx.x == 0) {
        psum[blockIdx.x] = wsum[0] + wsum[1] + wsum[2] + wsum[3];
        pfg[blockIdx.x] = wfg[0] | wfg[1] | wfg[2] | wfg[3];
    }
}

// ---------------------------------------------------------------------------
// Reduce 1024 block partials -> loss (byte-identical to R0).
// ---------------------------------------------------------------------------
__global__ __launch_bounds__(256) void k_finalize(const float* __restrict__ psum,
                                                  const int* __restrict__ pfg,
                                                  float* __restrict__ out) {
    int t = threadIdx.x;
    int b = t >> 6, l = t & 63;
    int base = (b << 8) + l;
    float s = psum[base] + psum[base + 64] + psum[base + 128] + psum[base + 192];
    int f = pfg[base] | pfg[base + 64] | pfg[base + 128] | pfg[base + 192];
    #pragma unroll
    for (int off = 32; off; off >>= 1) {
        s += __shfl_down(s, off, 64);
        f |= __shfl_down(f, off, 64);
    }
    __shared__ float bsum[4];
    __shared__ int bfg[4];
    if (l == 0) { bsum[b] = s; bfg[b] = f; }
    __syncthreads();
    if (t == 0) {
        float loss = 0.0f;
        for (int bb = 0; bb < BB; ++bb) {
            float lb = 1.0f - bsum[bb] * (1.0f / (float)HW);
            if (bfg[bb]) loss += lb;
        }
        loss *= (1.0f / (float)BB);
        if (isnan(loss)) loss = 0.0f;
        else if (isinf(loss)) loss = (loss > 0.0f) ? 1.0f : 0.0f;
        out[0] = loss;
    }
}

extern "C" void kernel_launch(void* const* d_in, const int* in_sizes, int n_in,
                              void* d_out, int out_size, void* d_ws, size_t ws_size,
                              hipStream_t stream) {
    (void)in_sizes; (void)n_in; (void)out_size; (void)ws_size;
    const float* pred = (const float*)d_in[0];   // [4,3,256,256] f32
    const int*   lab  = (const int*)d_in[1];     // [4,256,256] i32

    char* wsb = (char*)d_ws;
    float* dbuf   = (float*)wsb;                                  // 24*65536 f32 = 6 MB
    size_t off    = (size_t)NM * HW * sizeof(float);
    float* blkmax = (float*)(wsb + off);          off += 768 * sizeof(float);
    float* psum   = (float*)(wsb + off);          off += 1024 * sizeof(float);
    int*   pfg    = (int*)  (wsb + off);          off += 1024 * sizeof(int);
    unsigned char* codes = (unsigned char*)(wsb + off);           // 256 KB
    off += (size_t)BB * HW;
    off = (off + 255) & ~(size_t)255;
    unsigned long long* bits = (unsigned long long*)(wsb + off);  // 192 KB

    // Proven 4-launch topology (best measured sync structure); every scratch
    // word is written before it is read --- no memset needed.
    k_rowpass <<<NBLK,    256, 0, stream>>>(pred, lab, bits, codes);
    k_colpass <<<NM * 32, 256, 0, stream>>>(bits, dbuf, blkmax);
    k_final   <<<NBLK,    256, 0, stream>>>(codes, dbuf, blkmax, psum, pfg);
    k_finalize<<<1,       256, 0, stream>>>(psum, pfg, (float*)d_out);
}